// Round 15
// baseline (468.513 us; speedup 1.0000x reference)
//
#include <hip/hip_runtime.h>
#include <hip/hip_bf16.h>
#include <stdint.h>

typedef uint16_t u16;
typedef uint32_t u32;
typedef uint64_t u64;
typedef unsigned char u8;

#define TT 16384
#define ZZ 4096
#define EE 65536
#define LBLK 32
#define NBLK 512          // TT / LBLK
#define SUPW 16
#define NSUP 32           // NBLK / SUPW
#define ADJ_STRIDE 80     // u16 entries per row (max degree ~60 w.h.p.); 20 u64 chunks
#define UCAP 1024         // fast-path chain capacity; overflow -> exact table fallback
#define PEN 10.0f

// ---- ws layout (bytes) ----
#define WS_BITS   0x000000   // u32[4096*128]  2 MB   adjacency bitmask
#define WS_GMKEY  0x200000   // u64[16384]     128 KB scan-key (max,argmax) per r' row
#define WS_DEG    0x220000   // u32[4096]
#define WS_ADJL   0x224000   // u16[4096*80]   640 KB CSR (padded to mult of 4 w/ self)
#define WS_NCH    0x2C4000   // u8[4096]       padded chunk count (deg/4)
#define WS_CVEC   0x2C5000   // f32[128]
#define WS_WVEC   0x2C5200   // f32[128]
#define WS_H2     0x2C5400   // f32[16384*64]  4 MB  (dead after k_raw)
#define WS_M      WS_H2      // u16[512*4096]  4 MB  composed block maps (aliases h2)
#define WS_H      0x6C5400   // u16[32*4096]   256 KB super maps
#define WS_SB     0x705400   // u32[512]
#define WS_CUR    0x705C00   // u32[16384]     cur[t]

// sortable u32: bigger == larger float (total order incl. negatives)
__device__ __forceinline__ u32 sfu(float v) {
  u32 u = __float_as_uint(v);
  return u ^ ((u32)((int)u >> 31) | 0x80000000u);
}
// 44-bit scan key (k_raw/gmkey storage): sfu(v)<<12 | (4095-z)
__device__ __forceinline__ u64 mkkey(float v, u32 z) {
  return ((u64)sfu(v) << 12) | (u64)(4095u - z);
}
__device__ __forceinline__ float key_val(u64 k) {
  u32 sf = (u32)(k >> 12);
  u32 u = (sf & 0x80000000u) ? (sf ^ 0x80000000u) : ~sf;
  return __uint_as_float(u);
}

// one quarter of an eval: strided chunks {part, part+4, ..., part+16} of state s.
// Preloads guarded (R11-proven); nc from LDS table.
// In-register key pair: {hi = sf(value), lo = z^0xFFF} -> u64 max == (val, min-z).
__device__ __forceinline__ u64 eval_part(int s, int part, const u32* keys, u64 gkey,
                                         const u16* adjl, int nc) {
  const u64* alq = (const u64*)(adjl + (size_t)s * ADJ_STRIDE);
  u64 c0 = (part      < nc) ? alq[part]      : 0;
  u64 c1 = (part + 4  < nc) ? alq[part + 4]  : 0;
  u64 c2 = (part + 8  < nc) ? alq[part + 8]  : 0;
  u64 c3 = (part + 12 < nc) ? alq[part + 12] : 0;
  u64 c4 = (part + 16 < nc) ? alq[part + 16] : 0;
  u64 bb = gkey;
#define CM(cv, cnd) if (cnd) {                                                   \
    u32 lo = (u32)(cv), hi = (u32)((cv) >> 32);                                  \
    u32 za = lo & 0xFFFFu, zb = lo >> 16, zc = hi & 0xFFFFu, zd = hi >> 16;      \
    u64 k0 = ((u64)keys[za] << 32) | (u64)(za ^ 0xFFFu);                         \
    u64 k1 = ((u64)keys[zb] << 32) | (u64)(zb ^ 0xFFFu);                         \
    u64 k2 = ((u64)keys[zc] << 32) | (u64)(zc ^ 0xFFFu);                         \
    u64 k3 = ((u64)keys[zd] << 32) | (u64)(zd ^ 0xFFFu);                         \
    u64 t01 = k0 > k1 ? k0 : k1; u64 t23 = k2 > k3 ? k2 : k3;                    \
    u64 tm = t01 > t23 ? t01 : t23;                                              \
    bb = tm > bb ? tm : bb; }
  CM(c0, part < nc) CM(c1, part + 4 < nc) CM(c2, part + 8 < nc)
  CM(c3, part + 12 < nc) CM(c4, part + 16 < nc)
#undef CM
  return bb;
}

// ---- KA: fused {blocks 0..15: self loops} {block 16: cvec/wvec} ----
__global__ __launch_bounds__(256) void k_setupA(u32* bits, u32* deg, u16* adjl,
                                                const float* pa, const float* W1,
                                                const float* b1,
                                                float* cvec, float* wvec) {
  __shared__ float pal[512];
  int tid = threadIdx.x;
  if (blockIdx.x < 16) {
    int z = blockIdx.x * 256 + tid;
    bits[(size_t)z * 128 + (z >> 5)] = 1u << (z & 31);
    deg[z] = 1;
    adjl[(size_t)z * ADJ_STRIDE] = (u16)z;
    return;
  }
  for (int i = tid; i < 512; i += 256) pal[i] = pa[i];
  __syncthreads();
  if (tid < 128) {
    float acc = b1[tid];
    for (int i = 0; i < 512; i++) acc = fmaf(pal[i], W1[(size_t)i * 128 + tid], acc);
    cvec[tid] = acc;
    wvec[tid] = W1[512 * 128 + tid];
  }
}

// ---- K0b: scatter edges (deduped via bitmask old-value) ----
__global__ void k_edges(const int* ei, u32* bits, u32* deg, u16* adjl) {
  int e = blockIdx.x * blockDim.x + threadIdx.x;
  if (e >= EE) return;
  int u = ei[e], v = ei[EE + e];
#pragma unroll
  for (int dir = 0; dir < 2; dir++) {
    int a = dir ? v : u, b = dir ? u : v;
    u32 bit = 1u << (b & 31);
    u32 old = atomicOr(&bits[(size_t)a * 128 + (b >> 5)], bit);
    if (!(old & bit)) {
      u32 p = atomicAdd(&deg[a], 1u);
      if (p < ADJ_STRIDE) adjl[(size_t)a * ADJ_STRIDE + p] = (u16)b;
    }
  }
}

// ---- KC: fused {blocks 0..15: pad rows to mult4 + chunk count} {rest: h2 MLP} ----
__global__ __launch_bounds__(256) void k_setupC(const u32* deg, u16* adjl, u8* nchp,
                                                const float* times, const float* W2,
                                                const float* b2, const float* cvec,
                                                const float* wvec, float* h2) {
  __shared__ float W2T[64][132];
  __shared__ float h1b[4][128];
  __shared__ float cl[128], wl[128], b2l[64];
  int tid = threadIdx.x;
  if (blockIdx.x < 16) {
    int z = blockIdx.x * 256 + tid;
    int d = (int)deg[z]; if (d > ADJ_STRIDE) d = ADJ_STRIDE;
    int dp = (d + 3) & ~3;
    for (int k = d; k < dp; k++) adjl[(size_t)z * ADJ_STRIDE + k] = (u16)z;
    nchp[z] = (u8)(dp >> 2);
    return;
  }
  for (int idx = tid; idx < 128 * 64; idx += 256) {
    int i = idx >> 6, j = idx & 63;
    W2T[j][i] = W2[idx];
  }
  if (tid < 128) { cl[tid] = cvec[tid]; wl[tid] = wvec[tid]; }
  else if (tid < 192) b2l[tid - 128] = b2[tid - 128];
  __syncthreads();
  int w = tid >> 6, lane = tid & 63;
  int t = (blockIdx.x - 16) * 4 + w;
  float tv = times[t];
  h1b[w][lane]      = fmaxf(fmaf(tv, wl[lane],      cl[lane]),      0.f);
  h1b[w][lane + 64] = fmaxf(fmaf(tv, wl[lane + 64], cl[lane + 64]), 0.f);
  __syncthreads();
  float acc = b2l[lane];
  const float4* hr = (const float4*)&h1b[w][0];
  const float4* Wr = (const float4*)&W2T[lane][0];
#pragma unroll
  for (int i4 = 0; i4 < 32; i4++) {
    float4 a = hr[i4], bb = Wr[i4];
    acc += a.x * bb.x; acc += a.y * bb.y; acc += a.z * bb.z; acc += a.w * bb.w;
  }
  acc = fmaxf(acc, 0.f);
  h2[(size_t)t * 64 + lane] = acc;
}

// ---- K3: r' = h2@W3 + b3 - 10 -> d_out ; fused per-row (max,argmax) ----
// Proven 64t x 128z tile, 512 threads (4t x 4z per thread).
__global__ __launch_bounds__(512) void k_raw(const float* h2, const float* W3,
                                             const float* b3, float* out,
                                             u64* gmkey) {
  __shared__ float w3t[64][128];   // 32 KB
  __shared__ float h2t[64][72];    // 18 KB
  int tid = threadIdx.x;
  int zblk = blockIdx.x & 31, tblk = blockIdx.x >> 5;
  int z0 = zblk * 128, t0 = tblk * 64;
#pragma unroll
  for (int it = 0; it < 4; it++) {
    int f4 = tid + it * 512;                 // 2048 float4 = 8192 f32
    int k = f4 >> 5, jj = (f4 & 31) * 4;
    *(float4*)&w3t[k][jj] = *(const float4*)(W3 + (size_t)k * ZZ + z0 + jj);
  }
#pragma unroll
  for (int it = 0; it < 2; it++) {
    int f4 = tid + it * 512;                 // 1024 float4 = 4096 f32
    int r = f4 >> 4, kk = (f4 & 15) * 4;
    float4 h = *(const float4*)(h2 + (size_t)(t0 + r) * 64 + kk);
    h2t[kk + 0][r] = h.x; h2t[kk + 1][r] = h.y;
    h2t[kk + 2][r] = h.z; h2t[kk + 3][r] = h.w;
  }
  __syncthreads();
  int zq = tid & 31, tq = tid >> 5;          // 32 z-groups x 4z, 16 t-groups x 4t
  float4 acc[4];
#pragma unroll
  for (int r = 0; r < 4; r++) acc[r] = make_float4(0.f, 0.f, 0.f, 0.f);
  for (int k = 0; k < 64; k++) {
    float4 w = *(const float4*)&w3t[k][zq * 4];
    float4 h = *(const float4*)&h2t[k][tq * 4];
    acc[0].x += h.x * w.x; acc[0].y += h.x * w.y; acc[0].z += h.x * w.z; acc[0].w += h.x * w.w;
    acc[1].x += h.y * w.x; acc[1].y += h.y * w.y; acc[1].z += h.y * w.z; acc[1].w += h.y * w.w;
    acc[2].x += h.z * w.x; acc[2].y += h.z * w.y; acc[2].z += h.z * w.z; acc[2].w += h.z * w.w;
    acc[3].x += h.w * w.x; acc[3].y += h.w * w.y; acc[3].z += h.w * w.z; acc[3].w += h.w * w.w;
  }
  int z = z0 + zq * 4;
  float4 b3v = *(const float4*)(b3 + z);
  int lane = tid & 63;
  int half = lane >> 5;
#pragma unroll
  for (int r = 0; r < 4; r++) {
    int t = t0 + tq * 4 + r;
    float4 v;
    v.x = acc[r].x + b3v.x - PEN; v.y = acc[r].y + b3v.y - PEN;
    v.z = acc[r].z + b3v.z - PEN; v.w = acc[r].w + b3v.w - PEN;
    *(float4*)(out + (size_t)t * ZZ + z) = v;
    float lv = v.x; u32 lz = (u32)z;
    if (v.y > lv) { lv = v.y; lz = (u32)(z + 1); }
    if (v.z > lv) { lv = v.z; lz = (u32)(z + 2); }
    if (v.w > lv) { lv = v.w; lz = (u32)(z + 3); }
    float mv = lv;
#pragma unroll
    for (int off = 16; off >= 1; off >>= 1) {
      float o = __shfl_xor(mv, off);
      mv = o > mv ? o : mv;
    }
    u64 msk = __ballot(lv == mv);
    u32 hm = (u32)(msk >> (half * 32));
    int fl = __ffs(hm) - 1 + half * 32;
    u32 zbest = __shfl(lz, fl);
    if ((lane & 31) == 0)
      atomicMax((unsigned long long*)&gmkey[t], (unsigned long long)mkkey(mv, zbest));
  }
}

// ---- K4: per-block composed transition maps.
// iter0: dense eval -> ev0 (full domain), build image_0 chains.
// iters 1..31: m0 independent chains S[u] (4-lane teams, S in LDS, team-private),
// ONE barrier/iter (keys double-buffered: eval reads keys[cur], rekey writes
// keys[cur^1]). Final: R[U0[u]]=S[u]; M[j]=R[ev0[j]].
// Exact fallback (m0 > UCAP): full-domain table scan.
__global__ __launch_bounds__(512) void k_stage1(const float* raw, const u16* adjl,
                                                const u8* nchp, const u64* gmkey,
                                                u16* M) {
  __shared__ u32 keys[2][ZZ];  // 32 KB double-buffered key tables
  __shared__ u16 ev0[ZZ];      // 8 KB first-step map (persists)
  __shared__ u16 R[ZZ];        // 8 KB final remap over image_0 (or full domain)
  __shared__ u16 evf[ZZ];      // 8 KB fallback eval buffer
  __shared__ u16 U0[UCAP];     // 2 KB image_0 list
  __shared__ u16 S[UCAP];      // 2 KB chain states
  __shared__ u8  nchl[ZZ];     // 4 KB
  __shared__ u32 markw[128];
  __shared__ u32 mcnt;
  __shared__ u64 gmk[LBLK];
  int tid = threadIdx.x;
  int b = blockIdx.x, t0 = b * LBLK;
  *(u64*)&nchl[tid * 8] = *(const u64*)(nchp + tid * 8);
  if (tid < LBLK) gmk[tid] = gmkey[t0 + tid];
  {
    const float4* src = (const float4*)(raw + (size_t)t0 * ZZ);
    float4 r0 = src[tid], r1 = src[tid + 512];
    ((uint4*)keys[0])[tid]       = make_uint4(sfu(r0.x), sfu(r0.y), sfu(r0.z), sfu(r0.w));
    ((uint4*)keys[0])[tid + 512] = make_uint4(sfu(r1.x), sfu(r1.y), sfu(r1.z), sfu(r1.w));
  }
  if (tid < 128) markw[tid] = 0;
  if (tid == 128) mcnt = 0;
  __syncthreads();
  int lane = tid & 63;
  u64 lmask = (((u64)1) << lane) - 1ull;
  int part = tid & 3;
  // ---- iter 0: dense eval -> ev0; build U0/S; rekey row t0+1 -> keys[1] ----
  {
    const float4* srcn = (const float4*)(raw + (size_t)(t0 + 1) * ZZ);
    float4 p0 = srcn[tid], p1 = srcn[tid + 512];
    u64 gk = gmk[0];
    float gv = key_val(gk) - PEN;
    u64 gkey = ((u64)sfu(gv) << 32) | (u64)(gk & 0xFFFu);
    for (int u = tid; u < ZZ * 4; u += 512) {
      int s = u >> 2;
      u64 pk = eval_part(s, part, keys[0], gkey, adjl, (int)nchl[s]);
      u64 o1 = __shfl_xor(pk, 1); pk = o1 > pk ? o1 : pk;
      u64 o2 = __shfl_xor(pk, 2); pk = o2 > pk ? o2 : pk;
      if (part == 0) ev0[s] = (u16)(4095u - ((u32)pk & 0xFFFu));
    }
    __syncthreads();
    for (int ch = 0; ch < 8; ch++) {
      u32 ns = ev0[ch * 512 + tid];
      u32 wi = ns >> 5, bit = 1u << (ns & 31);
      u32 old = atomicOr(&markw[wi], bit);
      bool isnew = !(old & bit);
      u64 msk = __ballot(isnew ? 1 : 0);
      u32 base = 0;
      if (lane == 0) base = msk ? atomicAdd(&mcnt, (u32)__popcll(msk)) : 0u;
      base = __shfl(base, 0);
      if (isnew) {
        u32 idx = base + (u32)__popcll(msk & lmask);
        if (idx < UCAP) { U0[idx] = (u16)ns; S[idx] = (u16)ns; }
      }
    }
    ((uint4*)keys[1])[tid]       = make_uint4(sfu(p0.x), sfu(p0.y), sfu(p0.z), sfu(p0.w));
    ((uint4*)keys[1])[tid + 512] = make_uint4(sfu(p1.x), sfu(p1.y), sfu(p1.z), sfu(p1.w));
    __syncthreads();
  }
  int m0 = (int)mcnt;
  int cur = 1;
  if (m0 <= UCAP) {
    // ---- fast path: independent chains, one barrier per iter ----
    for (int i = 1; i < LBLK; i++) {
      int tn = t0 + i + 1; if (tn > TT - 1) tn = TT - 1;
      const float4* srcn = (const float4*)(raw + (size_t)tn * ZZ);
      float4 p0 = srcn[tid], p1 = srcn[tid + 512];
      u64 gk = gmk[i];
      float gv = key_val(gk) - PEN;
      u64 gkey = ((u64)sfu(gv) << 32) | (u64)(gk & 0xFFFu);
      const u32* kc = keys[cur];
      for (int u = tid >> 2; u < m0; u += 128) {
        int s = (int)S[u];
        u64 pk = eval_part(s, part, kc, gkey, adjl, (int)nchl[s]);
        u64 o1 = __shfl_xor(pk, 1); pk = o1 > pk ? o1 : pk;
        u64 o2 = __shfl_xor(pk, 2); pk = o2 > pk ? o2 : pk;
        if (part == 0) S[u] = (u16)(4095u - ((u32)pk & 0xFFFu));
      }
      u32* kn = keys[cur ^ 1];
      ((uint4*)kn)[tid]       = make_uint4(sfu(p0.x), sfu(p0.y), sfu(p0.z), sfu(p0.w));
      ((uint4*)kn)[tid + 512] = make_uint4(sfu(p1.x), sfu(p1.y), sfu(p1.z), sfu(p1.w));
      __syncthreads();
      cur ^= 1;
    }
    for (int u = tid; u < m0; u += 512) R[U0[u]] = S[u];
    __syncthreads();
  } else {
    // ---- exact fallback: full-domain table scan (insurance; not expected) ----
#pragma unroll
    for (int q = 0; q < 8; q++) { int j = tid + q * 512; R[j] = (u16)j; }
    __syncthreads();
    for (int i = 1; i < LBLK; i++) {
      int tn = t0 + i + 1; if (tn > TT - 1) tn = TT - 1;
      const float4* srcn = (const float4*)(raw + (size_t)tn * ZZ);
      float4 p0 = srcn[tid], p1 = srcn[tid + 512];
      u64 gk = gmk[i];
      float gv = key_val(gk) - PEN;
      u64 gkey = ((u64)sfu(gv) << 32) | (u64)(gk & 0xFFFu);
      const u32* kc = keys[cur];
      for (int u = tid; u < ZZ * 4; u += 512) {
        int s = u >> 2;
        u64 pk = eval_part(s, part, kc, gkey, adjl, (int)nchl[s]);
        u64 o1 = __shfl_xor(pk, 1); pk = o1 > pk ? o1 : pk;
        u64 o2 = __shfl_xor(pk, 2); pk = o2 > pk ? o2 : pk;
        if (part == 0) evf[s] = (u16)(4095u - ((u32)pk & 0xFFFu));
      }
      __syncthreads();
#pragma unroll
      for (int q = 0; q < 8; q++) { int j = tid + q * 512; R[j] = evf[R[j]]; }
      u32* kn = keys[cur ^ 1];
      ((uint4*)kn)[tid]       = make_uint4(sfu(p0.x), sfu(p0.y), sfu(p0.z), sfu(p0.w));
      ((uint4*)kn)[tid + 512] = make_uint4(sfu(p1.x), sfu(p1.y), sfu(p1.z), sfu(p1.w));
      __syncthreads();
      cur ^= 1;
    }
  }
  // ---- final expansion: M[j] = R[ev0[j]] ----
  {
    int j0 = tid * 8;
    u64 w0 = (u64)R[ev0[j0 + 0]]
           | ((u64)R[ev0[j0 + 1]] << 16)
           | ((u64)R[ev0[j0 + 2]] << 32)
           | ((u64)R[ev0[j0 + 3]] << 48);
    u64 w1 = (u64)R[ev0[j0 + 4]]
           | ((u64)R[ev0[j0 + 5]] << 16)
           | ((u64)R[ev0[j0 + 6]] << 32)
           | ((u64)R[ev0[j0 + 7]] << 48);
    u64* md = (u64*)(M + (size_t)b * ZZ);
    md[tid * 2]     = w0;
    md[tid * 2 + 1] = w1;
  }
}

// ---- K5a: compose groups of 16 block-maps into super maps ----
__global__ __launch_bounds__(256) void k_super(const u16* G, u16* H) {
  int g = blockIdx.x, tid = threadIdx.x;
  u32 v[16];
#pragma unroll
  for (int q = 0; q < 16; q++) v[q] = G[(size_t)(g * SUPW) * ZZ + tid + q * 256];
  for (int k = 1; k < SUPW; k++) {
    const u16* Gk = G + (size_t)(g * SUPW + k) * ZZ;
#pragma unroll
    for (int q = 0; q < 16; q++) v[q] = Gk[v[q]];
  }
#pragma unroll
  for (int q = 0; q < 16; q++) H[(size_t)g * ZZ + tid + q * 256] = (u16)v[q];
}

// ---- K5b: chase super maps then per-group block maps -> block start states ----
__global__ void k_chase(const u16* G, const u16* H, u32* sb) {
  __shared__ u32 ug[NSUP];
  int tid = threadIdx.x;  // 64
  if (tid == 0) {
    u32 s = 0;
    for (int g = 0; g < NSUP; g++) { ug[g] = s; s = H[(size_t)g * ZZ + s]; }
  }
  __syncthreads();
  if (tid < NSUP) {
    u32 s = ug[tid];
    for (int k = 0; k < SUPW; k++) {
      int b = tid * SUPW + k;
      sb[b] = s;
      s = G[(size_t)b * ZZ + s];
    }
  }
}

// ---- K6: one wave per scan-block walks its steps (all blocks co-resident) ----
__global__ __launch_bounds__(64) void k_replay2(const float* out, const u16* adjl,
                                                const u8* nchp, const u64* gmkey,
                                                const u32* sb, u32* curz) {
  int b = blockIdx.x, t0 = b * LBLK;
  int lane = threadIdx.x;
  u32 s = sb[b];
  for (int i = 0; i < LBLK; i++) {
    int t = t0 + i;
    if (lane == 0) curz[t] = s;
    u64 gk = gmkey[t];
    float gv = key_val(gk) - PEN;
    u32 gi = 4095u - (u32)(gk & 0xFFFu);
    int dp = ((int)nchp[s]) << 2;
    const u16* al = adjl + (size_t)s * ADJ_STRIDE;
    const float* r = out + (size_t)t * ZZ;
    float bv = gv; u32 bi = gi;
    if (lane < dp) {
      u32 nb = al[lane]; float v = r[nb];
      if (v > bv || (v == bv && nb < bi)) { bv = v; bi = nb; }
    }
    if (lane + 64 < dp) {
      u32 nb = al[lane + 64]; float v = r[nb];
      if (v > bv || (v == bv && nb < bi)) { bv = v; bi = nb; }
    }
#pragma unroll
    for (int off = 32; off >= 1; off >>= 1) {
      float ov = __shfl_xor(bv, off);
      u32 oi  = __shfl_xor(bi, off);
      if (ov > bv || (ov == bv && oi < bi)) { bv = ov; bi = oi; }
    }
    s = bi;
  }
}

// ---- K7: sparse final update: out[t][z] += 10 for z adjacent to cur[t] ----
__global__ __launch_bounds__(256) void k_out2(float* out, const u32* curz, const u32* bits) {
  int t = blockIdx.x * 4 + (threadIdx.x >> 6);
  int lane = threadIdx.x & 63;
  u32 c = curz[t];
  u64 w = ((const u64*)(bits + (size_t)c * 128))[lane];
  float* p = out + (size_t)t * ZZ + lane * 64;
  while (w) {
    int bpos = __ffsll((unsigned long long)w) - 1;
    p[bpos] += PEN;
    w &= w - 1;
  }
}

extern "C" void kernel_launch(void* const* d_in, const int* in_sizes, int n_in,
                              void* d_out, int out_size, void* d_ws, size_t ws_size,
                              hipStream_t stream) {
  const float* pa    = (const float*)d_in[0];
  const float* times = (const float*)d_in[1];
  const int*   ei    = (const int*)d_in[3];
  const float* W1    = (const float*)d_in[4];
  const float* b1    = (const float*)d_in[5];
  const float* W2    = (const float*)d_in[6];
  const float* b2    = (const float*)d_in[7];
  const float* W3    = (const float*)d_in[8];
  const float* b3    = (const float*)d_in[9];
  float* out = (float*)d_out;
  char* ws = (char*)d_ws;

  u32* bits = (u32*)(ws + WS_BITS);
  u64* gmkey = (u64*)(ws + WS_GMKEY);
  u32* deg  = (u32*)(ws + WS_DEG);
  u16* adjl = (u16*)(ws + WS_ADJL);
  u8*  nchp = (u8*)(ws + WS_NCH);
  float* cvec = (float*)(ws + WS_CVEC);
  float* wvec = (float*)(ws + WS_WVEC);
  float* h2   = (float*)(ws + WS_H2);
  u16* M = (u16*)(ws + WS_M);
  u16* H = (u16*)(ws + WS_H);
  u32* sb   = (u32*)(ws + WS_SB);
  u32* curz = (u32*)(ws + WS_CUR);

  hipMemsetAsync(ws, 0, 0x220000, stream);  // bits + gmkey
  hipLaunchKernelGGL(k_setupA, dim3(17), dim3(256), 0, stream,
                     bits, deg, adjl, pa, W1, b1, cvec, wvec);
  hipLaunchKernelGGL(k_edges, dim3(EE / 256), dim3(256), 0, stream, ei, bits, deg, adjl);
  hipLaunchKernelGGL(k_setupC, dim3(16 + TT / 4), dim3(256), 0, stream,
                     deg, adjl, nchp, times, W2, b2, cvec, wvec, h2);
  hipLaunchKernelGGL(k_raw, dim3(8192), dim3(512), 0, stream, h2, W3, b3, out, gmkey);
  hipLaunchKernelGGL(k_stage1, dim3(NBLK), dim3(512), 0, stream, out, adjl, nchp, gmkey, M);
  hipLaunchKernelGGL(k_super, dim3(NSUP), dim3(256), 0, stream, M, H);
  hipLaunchKernelGGL(k_chase, dim3(1), dim3(64), 0, stream, M, H, sb);
  hipLaunchKernelGGL(k_replay2, dim3(NBLK), dim3(64), 0, stream, out, adjl, nchp, gmkey, sb, curz);
  hipLaunchKernelGGL(k_out2, dim3(TT / 4), dim3(256), 0, stream, out, curz, bits);
}

// Round 16
// 399.461 us; speedup vs baseline: 1.1729x; 1.1729x over previous
//
#include <hip/hip_runtime.h>
#include <hip/hip_bf16.h>
#include <stdint.h>

typedef uint16_t u16;
typedef uint32_t u32;
typedef uint64_t u64;
typedef unsigned char u8;

#define TT 16384
#define ZZ 4096
#define EE 65536
#define LBLK 32
#define NBLK 512          // TT / LBLK
#define SUPW 16
#define NSUP 32           // NBLK / SUPW
#define ADJ_STRIDE 80     // u16 entries per row (max degree ~60 w.h.p.); 20 u64 chunks
#define UCAP 2048         // worklist cap; overflow -> exact dense fallback
#define PEN 10.0f

// ---- ws layout (bytes) ----
#define WS_BITS   0x000000   // u32[4096*128]  2 MB   adjacency bitmask
#define WS_GMKEY  0x200000   // u64[16384]     128 KB scan-key (max,argmax) per r' row
#define WS_DEG    0x220000   // u32[4096]
#define WS_ADJL   0x224000   // u16[4096*80]   640 KB CSR (padded to mult of 4 w/ self)
#define WS_NCH    0x2C4000   // u8[4096]       padded chunk count (deg/4)
#define WS_CVEC   0x2C5000   // f32[128]
#define WS_WVEC   0x2C5200   // f32[128]
#define WS_H2     0x2C5400   // f32[16384*64]  4 MB  (dead after k_raw)
#define WS_M      WS_H2      // u16[512*4096]  4 MB  composed block maps (aliases h2)
#define WS_H      0x6C5400   // u16[32*4096]   256 KB super maps
#define WS_SB     0x705400   // u32[512]
#define WS_CUR    0x705C00   // u32[16384]     cur[t]

// sortable u32: bigger == larger float (total order incl. negatives)
__device__ __forceinline__ u32 sfu(float v) {
  u32 u = __float_as_uint(v);
  return u ^ ((u32)((int)u >> 31) | 0x80000000u);
}
// 44-bit scan key (k_raw/gmkey storage): sfu(v)<<12 | (4095-z)
__device__ __forceinline__ u64 mkkey(float v, u32 z) {
  return ((u64)sfu(v) << 12) | (u64)(4095u - z);
}
__device__ __forceinline__ float key_val(u64 k) {
  u32 sf = (u32)(k >> 12);
  u32 u = (sf & 0x80000000u) ? (sf ^ 0x80000000u) : ~sf;
  return __uint_as_float(u);
}

// one quarter of an eval: strided chunks {part, part+4, ..., part+16} of state s.
// Preloads guarded (R11-proven); nc from LDS table.
// In-register key pair: {hi = sf(value), lo = z^0xFFF} -> u64 max == (val, min-z).
__device__ __forceinline__ u64 eval_part(int s, int part, const u32* keys, u64 gkey,
                                         const u16* adjl, int nc) {
  const u64* alq = (const u64*)(adjl + (size_t)s * ADJ_STRIDE);
  u64 c0 = (part      < nc) ? alq[part]      : 0;
  u64 c1 = (part + 4  < nc) ? alq[part + 4]  : 0;
  u64 c2 = (part + 8  < nc) ? alq[part + 8]  : 0;
  u64 c3 = (part + 12 < nc) ? alq[part + 12] : 0;
  u64 c4 = (part + 16 < nc) ? alq[part + 16] : 0;
  u64 bb = gkey;
#define CM(cv, cnd) if (cnd) {                                                   \
    u32 lo = (u32)(cv), hi = (u32)((cv) >> 32);                                  \
    u32 za = lo & 0xFFFFu, zb = lo >> 16, zc = hi & 0xFFFFu, zd = hi >> 16;      \
    u64 k0 = ((u64)keys[za] << 32) | (u64)(za ^ 0xFFFu);                         \
    u64 k1 = ((u64)keys[zb] << 32) | (u64)(zb ^ 0xFFFu);                         \
    u64 k2 = ((u64)keys[zc] << 32) | (u64)(zc ^ 0xFFFu);                         \
    u64 k3 = ((u64)keys[zd] << 32) | (u64)(zd ^ 0xFFFu);                         \
    u64 t01 = k0 > k1 ? k0 : k1; u64 t23 = k2 > k3 ? k2 : k3;                    \
    u64 tm = t01 > t23 ? t01 : t23;                                              \
    bb = tm > bb ? tm : bb; }
  CM(c0, part < nc) CM(c1, part + 4 < nc) CM(c2, part + 8 < nc)
  CM(c3, part + 12 < nc) CM(c4, part + 16 < nc)
#undef CM
  return bb;
}

// ---- KA: fused {zero bits+gmkey} {deg=0} {block last: cvec/wvec} ----
// grid = 545 blocks x 256 thr: blocks 0..543 zero 2.125MB (bits+gmkey) via
// float4 grid-stride; block 544 computes cvec. deg zeroed by blocks 0..15.
__global__ __launch_bounds__(256) void k_setupA(u32* bits, u32* deg,
                                                const float* pa, const float* W1,
                                                const float* b1,
                                                float* cvec, float* wvec) {
  __shared__ float pal[512];
  int tid = threadIdx.x;
  if (blockIdx.x < 544) {
    // zero bits (2 MB) + gmkey (128 KB) = 2.125 MB = 139264 uint4
    int idx = blockIdx.x * 256 + tid;
    ((uint4*)bits)[idx] = make_uint4(0, 0, 0, 0);
    if (blockIdx.x < 16) deg[blockIdx.x * 256 + tid] = 0;
    return;
  }
  for (int i = tid; i < 512; i += 256) pal[i] = pa[i];
  __syncthreads();
  if (tid < 128) {
    float acc = b1[tid];
    for (int i = 0; i < 512; i++) acc = fmaf(pal[i], W1[(size_t)i * 128 + tid], acc);
    cvec[tid] = acc;
    wvec[tid] = W1[512 * 128 + tid];
  }
}

// ---- K0b: scatter edges + self loops (blocks >= EE/256), deduped via bitmask ----
__global__ void k_edges(const int* ei, u32* bits, u32* deg, u16* adjl) {
  int gb = blockIdx.x;
  if (gb >= EE / 256) {
    // self-loop insertion through the same dedup path
    int z = (gb - EE / 256) * 256 + threadIdx.x;
    u32 bit = 1u << (z & 31);
    u32 old = atomicOr(&bits[(size_t)z * 128 + (z >> 5)], bit);
    if (!(old & bit)) {
      u32 p = atomicAdd(&deg[z], 1u);
      if (p < ADJ_STRIDE) adjl[(size_t)z * ADJ_STRIDE + p] = (u16)z;
    }
    return;
  }
  int e = gb * 256 + threadIdx.x;
  int u = ei[e], v = ei[EE + e];
#pragma unroll
  for (int dir = 0; dir < 2; dir++) {
    int a = dir ? v : u, b = dir ? u : v;
    u32 bit = 1u << (b & 31);
    u32 old = atomicOr(&bits[(size_t)a * 128 + (b >> 5)], bit);
    if (!(old & bit)) {
      u32 p = atomicAdd(&deg[a], 1u);
      if (p < ADJ_STRIDE) adjl[(size_t)a * ADJ_STRIDE + p] = (u16)b;
    }
  }
}

// ---- KC: fused {blocks 0..15: pad rows to mult4 + chunk count} {rest: h2 MLP} ----
__global__ __launch_bounds__(256) void k_setupC(const u32* deg, u16* adjl, u8* nchp,
                                                const float* times, const float* W2,
                                                const float* b2, const float* cvec,
                                                const float* wvec, float* h2) {
  __shared__ float W2T[64][132];
  __shared__ float h1b[4][128];
  __shared__ float cl[128], wl[128], b2l[64];
  int tid = threadIdx.x;
  if (blockIdx.x < 16) {
    int z = blockIdx.x * 256 + tid;
    int d = (int)deg[z]; if (d > ADJ_STRIDE) d = ADJ_STRIDE;
    int dp = (d + 3) & ~3;
    for (int k = d; k < dp; k++) adjl[(size_t)z * ADJ_STRIDE + k] = (u16)z;
    nchp[z] = (u8)(dp >> 2);
    return;
  }
  for (int idx = tid; idx < 128 * 64; idx += 256) {
    int i = idx >> 6, j = idx & 63;
    W2T[j][i] = W2[idx];
  }
  if (tid < 128) { cl[tid] = cvec[tid]; wl[tid] = wvec[tid]; }
  else if (tid < 192) b2l[tid - 128] = b2[tid - 128];
  __syncthreads();
  int w = tid >> 6, lane = tid & 63;
  int t = (blockIdx.x - 16) * 4 + w;
  float tv = times[t];
  h1b[w][lane]      = fmaxf(fmaf(tv, wl[lane],      cl[lane]),      0.f);
  h1b[w][lane + 64] = fmaxf(fmaf(tv, wl[lane + 64], cl[lane + 64]), 0.f);
  __syncthreads();
  float acc = b2l[lane];
  const float4* hr = (const float4*)&h1b[w][0];
  const float4* Wr = (const float4*)&W2T[lane][0];
#pragma unroll
  for (int i4 = 0; i4 < 32; i4++) {
    float4 a = hr[i4], bb = Wr[i4];
    acc += a.x * bb.x; acc += a.y * bb.y; acc += a.z * bb.z; acc += a.w * bb.w;
  }
  acc = fmaxf(acc, 0.f);
  h2[(size_t)t * 64 + lane] = acc;
}

// ---- K3: r' = h2@W3 + b3 - 10 -> d_out ; fused per-row (max,argmax) ----
// Proven 64t x 128z tile, 512 threads (4t x 4z per thread).
__global__ __launch_bounds__(512) void k_raw(const float* h2, const float* W3,
                                             const float* b3, float* out,
                                             u64* gmkey) {
  __shared__ float w3t[64][128];   // 32 KB
  __shared__ float h2t[64][72];    // 18 KB
  int tid = threadIdx.x;
  int zblk = blockIdx.x & 31, tblk = blockIdx.x >> 5;
  int z0 = zblk * 128, t0 = tblk * 64;
#pragma unroll
  for (int it = 0; it < 4; it++) {
    int f4 = tid + it * 512;                 // 2048 float4 = 8192 f32
    int k = f4 >> 5, jj = (f4 & 31) * 4;
    *(float4*)&w3t[k][jj] = *(const float4*)(W3 + (size_t)k * ZZ + z0 + jj);
  }
#pragma unroll
  for (int it = 0; it < 2; it++) {
    int f4 = tid + it * 512;                 // 1024 float4 = 4096 f32
    int r = f4 >> 4, kk = (f4 & 15) * 4;
    float4 h = *(const float4*)(h2 + (size_t)(t0 + r) * 64 + kk);
    h2t[kk + 0][r] = h.x; h2t[kk + 1][r] = h.y;
    h2t[kk + 2][r] = h.z; h2t[kk + 3][r] = h.w;
  }
  __syncthreads();
  int zq = tid & 31, tq = tid >> 5;          // 32 z-groups x 4z, 16 t-groups x 4t
  float4 acc[4];
#pragma unroll
  for (int r = 0; r < 4; r++) acc[r] = make_float4(0.f, 0.f, 0.f, 0.f);
  for (int k = 0; k < 64; k++) {
    float4 w = *(const float4*)&w3t[k][zq * 4];
    float4 h = *(const float4*)&h2t[k][tq * 4];
    acc[0].x += h.x * w.x; acc[0].y += h.x * w.y; acc[0].z += h.x * w.z; acc[0].w += h.x * w.w;
    acc[1].x += h.y * w.x; acc[1].y += h.y * w.y; acc[1].z += h.y * w.z; acc[1].w += h.y * w.w;
    acc[2].x += h.z * w.x; acc[2].y += h.z * w.y; acc[2].z += h.z * w.z; acc[2].w += h.z * w.w;
    acc[3].x += h.w * w.x; acc[3].y += h.w * w.y; acc[3].z += h.w * w.z; acc[3].w += h.w * w.w;
  }
  int z = z0 + zq * 4;
  float4 b3v = *(const float4*)(b3 + z);
  int lane = tid & 63;
  int half = lane >> 5;
#pragma unroll
  for (int r = 0; r < 4; r++) {
    int t = t0 + tq * 4 + r;
    float4 v;
    v.x = acc[r].x + b3v.x - PEN; v.y = acc[r].y + b3v.y - PEN;
    v.z = acc[r].z + b3v.z - PEN; v.w = acc[r].w + b3v.w - PEN;
    *(float4*)(out + (size_t)t * ZZ + z) = v;
    float lv = v.x; u32 lz = (u32)z;
    if (v.y > lv) { lv = v.y; lz = (u32)(z + 1); }
    if (v.z > lv) { lv = v.z; lz = (u32)(z + 2); }
    if (v.w > lv) { lv = v.w; lz = (u32)(z + 3); }
    float mv = lv;
#pragma unroll
    for (int off = 16; off >= 1; off >>= 1) {
      float o = __shfl_xor(mv, off);
      mv = o > mv ? o : mv;
    }
    u64 msk = __ballot(lv == mv);
    u32 hm = (u32)(msk >> (half * 32));
    int fl = __ffs(hm) - 1 + half * 32;
    u32 zbest = __shfl(lz, fl);
    if ((lane & 31) == 0)
      atomicMax((unsigned long long*)&gmkey[t], (unsigned long long)mkkey(mv, zbest));
  }
}

// ---- K4: per-block composed transition maps (R14-proven).
// ev0 = dense f_t0 map (computed once); R (on image_0 only) composes
// f_{t0+1..}; final M[j] = R[ev0[j]]. Worklist contracts each iter.
__global__ __launch_bounds__(512) void k_stage1(const float* raw, const u16* adjl,
                                                const u8* nchp, const u64* gmkey,
                                                u16* M) {
  __shared__ u32 keys[ZZ];     // 16 KB sortable-f32 table
  __shared__ u16 ev0[ZZ];      // 8 KB first-step map (full domain, persists)
  __shared__ u16 ev[ZZ];       // 8 KB current-step map (image domain)
  __shared__ u16 R[ZZ];        // 8 KB composed remap over image_0
  __shared__ u16 U0[UCAP];     // 4 KB image_0 list (persists)
  __shared__ u16 U[2][UCAP];   // 8 KB worklists
  __shared__ u8  nchl[ZZ];     // 4 KB
  __shared__ u32 markw[128];
  __shared__ u32 mcnt2[2];
  __shared__ u64 gmk[LBLK];
  int tid = threadIdx.x;
  int b = blockIdx.x, t0 = b * LBLK;
  *(u64*)&nchl[tid * 8] = *(const u64*)(nchp + tid * 8);
  if (tid < LBLK) gmk[tid] = gmkey[t0 + tid];
  {
    const float4* src = (const float4*)(raw + (size_t)t0 * ZZ);
    float4 r0 = src[tid], r1 = src[tid + 512];
    ((uint4*)keys)[tid]       = make_uint4(sfu(r0.x), sfu(r0.y), sfu(r0.z), sfu(r0.w));
    ((uint4*)keys)[tid + 512] = make_uint4(sfu(r1.x), sfu(r1.y), sfu(r1.z), sfu(r1.w));
  }
  if (tid < 128) markw[tid] = 0;
  if (tid == 128) { mcnt2[0] = 0; mcnt2[1] = 0; }
  __syncthreads();
  int lane = tid & 63;
  u64 lmask = (((u64)1) << lane) - 1ull;
  int part = tid & 3;
  // ---- iter 0: dense eval -> ev0 (full domain) ----
  {
    const float4* srcn = (const float4*)(raw + (size_t)(t0 + 1) * ZZ);
    float4 p0 = srcn[tid], p1 = srcn[tid + 512];
    u64 gk = gmk[0];
    float gv = key_val(gk) - PEN;
    u64 gkey = ((u64)sfu(gv) << 32) | (u64)(gk & 0xFFFu);
    for (int u = tid; u < ZZ * 4; u += 512) {
      int s = u >> 2;
      u64 pk = eval_part(s, part, keys, gkey, adjl, (int)nchl[s]);
      u64 o1 = __shfl_xor(pk, 1); pk = o1 > pk ? o1 : pk;
      u64 o2 = __shfl_xor(pk, 2); pk = o2 > pk ? o2 : pk;
      if (part == 0) ev0[s] = (u16)(4095u - ((u32)pk & 0xFFFu));
    }
    __syncthreads();
    // build image_0 worklist (U[0] + U0) and init R=identity on image_0
    for (int ch = 0; ch < 8; ch++) {
      u32 ns = ev0[ch * 512 + tid];
      u32 wi = ns >> 5, bit = 1u << (ns & 31);
      u32 old = atomicOr(&markw[wi], bit);
      bool isnew = !(old & bit);
      u64 msk = __ballot(isnew ? 1 : 0);
      u32 base = 0;
      if (lane == 0) base = msk ? atomicAdd(&mcnt2[0], (u32)__popcll(msk)) : 0u;
      base = __shfl(base, 0);
      if (isnew) {
        u32 idx = base + (u32)__popcll(msk & lmask);
        if (idx < UCAP) { U[0][idx] = (u16)ns; U0[idx] = (u16)ns; }
        R[ns] = (u16)ns;
      }
    }
    ((uint4*)keys)[tid]       = make_uint4(sfu(p0.x), sfu(p0.y), sfu(p0.z), sfu(p0.w));
    ((uint4*)keys)[tid + 512] = make_uint4(sfu(p1.x), sfu(p1.y), sfu(p1.z), sfu(p1.w));
    __syncthreads();
  }
  int m0r = (int)mcnt2[0];
  bool full0 = (m0r > UCAP);
  int m0 = full0 ? ZZ : m0r;
  if (full0) {                       // rare exact fallback: R = identity everywhere
#pragma unroll
    for (int q = 0; q < 8; q++) {
      int j = tid + q * 512;
      R[j] = (u16)j;
    }
    __syncthreads();
  }
  int m = m0;
  bool dense = full0;
  int pb = 0;
  for (int i = 1; i < LBLK; i++) {
    int t = t0 + i;
    // ---- phase A: prefetch next row, clear dedup state, eval worklist ----
    int tn = t + 1; if (tn > TT - 1) tn = TT - 1;
    const float4* srcn = (const float4*)(raw + (size_t)tn * ZZ);
    float4 p0 = srcn[tid], p1 = srcn[tid + 512];
    if (tid < 128) markw[tid] = 0;
    if (tid == 128) mcnt2[pb ^ 1] = 0;
    u64 gk = gmk[i];
    float gv = key_val(gk) - PEN;
    u64 gkey = ((u64)sfu(gv) << 32) | (u64)(gk & 0xFFFu);
    int m4 = m << 2;
    for (int u = tid; u < m4; u += 512) {
      int s = dense ? (u >> 2) : (int)U[pb][u >> 2];
      u64 pk = eval_part(s, part, keys, gkey, adjl, (int)nchl[s]);
      u64 o1 = __shfl_xor(pk, 1); pk = o1 > pk ? o1 : pk;
      u64 o2 = __shfl_xor(pk, 2); pk = o2 > pk ? o2 : pk;
      if (part == 0) ev[s] = (u16)(4095u - ((u32)pk & 0xFFFu));
    }
    __syncthreads();
    // ---- phase B: update R on image_0, dedup new image, re-key row ----
    for (int u = tid; u < m0; u += 512) {
      int v = full0 ? u : (int)U0[u];
      R[v] = ev[R[v]];
    }
    for (int u = tid; u < m; u += 512) {
      int s = dense ? u : (int)U[pb][u];
      u32 ns = ev[s];
      u32 wi = ns >> 5, bit = 1u << (ns & 31);
      u32 old = atomicOr(&markw[wi], bit);
      bool isnew = !(old & bit);
      u64 msk = __ballot(isnew ? 1 : 0);
      u32 base = 0;
      if (lane == 0) base = msk ? atomicAdd(&mcnt2[pb ^ 1], (u32)__popcll(msk)) : 0u;
      base = __shfl(base, 0);
      if (isnew) {
        u32 idx = base + (u32)__popcll(msk & lmask);
        if (idx < UCAP) U[pb ^ 1][idx] = (u16)ns;
      }
    }
    ((uint4*)keys)[tid]       = make_uint4(sfu(p0.x), sfu(p0.y), sfu(p0.z), sfu(p0.w));
    ((uint4*)keys)[tid + 512] = make_uint4(sfu(p1.x), sfu(p1.y), sfu(p1.z), sfu(p1.w));
    __syncthreads();
    m = (int)mcnt2[pb ^ 1];
    dense = (m > UCAP);
    if (dense) m = ZZ;
    pb ^= 1;
  }
  // ---- final expansion: M[j] = R[ev0[j]] ----
  {
    int j0 = tid * 8;
    u64 w0 = (u64)R[ev0[j0 + 0]]
           | ((u64)R[ev0[j0 + 1]] << 16)
           | ((u64)R[ev0[j0 + 2]] << 32)
           | ((u64)R[ev0[j0 + 3]] << 48);
    u64 w1 = (u64)R[ev0[j0 + 4]]
           | ((u64)R[ev0[j0 + 5]] << 16)
           | ((u64)R[ev0[j0 + 6]] << 32)
           | ((u64)R[ev0[j0 + 7]] << 48);
    u64* md = (u64*)(M + (size_t)b * ZZ);
    md[tid * 2]     = w0;
    md[tid * 2 + 1] = w1;
  }
}

// ---- K5a: compose groups of 16 block-maps into super maps.
// 128 blocks: group g = blockIdx>>2, domain quarter = blockIdx&3 (1024 entries).
__global__ __launch_bounds__(256) void k_super(const u16* G, u16* H) {
  int g = blockIdx.x >> 2, qtr = blockIdx.x & 3;
  int tid = threadIdx.x;
  int base = qtr * 1024;
  u32 v[4];
#pragma unroll
  for (int q = 0; q < 4; q++) v[q] = G[(size_t)(g * SUPW) * ZZ + base + tid + q * 256];
  for (int k = 1; k < SUPW; k++) {
    const u16* Gk = G + (size_t)(g * SUPW + k) * ZZ;
#pragma unroll
    for (int q = 0; q < 4; q++) v[q] = Gk[v[q]];
  }
#pragma unroll
  for (int q = 0; q < 4; q++) H[(size_t)g * ZZ + base + tid + q * 256] = (u16)v[q];
}

// ---- K5b: chase super maps then per-group block maps -> block start states ----
__global__ void k_chase(const u16* G, const u16* H, u32* sb) {
  __shared__ u32 ug[NSUP];
  int tid = threadIdx.x;  // 64
  if (tid == 0) {
    u32 s = 0;
    for (int g = 0; g < NSUP; g++) { ug[g] = s; s = H[(size_t)g * ZZ + s]; }
  }
  __syncthreads();
  if (tid < NSUP) {
    u32 s = ug[tid];
    for (int k = 0; k < SUPW; k++) {
      int b = tid * SUPW + k;
      sb[b] = s;
      s = G[(size_t)b * ZZ + s];
    }
  }
}

// ---- K6: one wave per scan-block walks its steps (all blocks co-resident) ----
__global__ __launch_bounds__(64) void k_replay2(const float* out, const u16* adjl,
                                                const u8* nchp, const u64* gmkey,
                                                const u32* sb, u32* curz) {
  int b = blockIdx.x, t0 = b * LBLK;
  int lane = threadIdx.x;
  u32 s = sb[b];
  for (int i = 0; i < LBLK; i++) {
    int t = t0 + i;
    if (lane == 0) curz[t] = s;
    u64 gk = gmkey[t];
    float gv = key_val(gk) - PEN;
    u32 gi = 4095u - (u32)(gk & 0xFFFu);
    int dp = ((int)nchp[s]) << 2;
    const u16* al = adjl + (size_t)s * ADJ_STRIDE;
    const float* r = out + (size_t)t * ZZ;
    float bv = gv; u32 bi = gi;
    if (lane < dp) {
      u32 nb = al[lane]; float v = r[nb];
      if (v > bv || (v == bv && nb < bi)) { bv = v; bi = nb; }
    }
    if (lane + 64 < dp) {
      u32 nb = al[lane + 64]; float v = r[nb];
      if (v > bv || (v == bv && nb < bi)) { bv = v; bi = nb; }
    }
#pragma unroll
    for (int off = 32; off >= 1; off >>= 1) {
      float ov = __shfl_xor(bv, off);
      u32 oi  = __shfl_xor(bi, off);
      if (ov > bv || (ov == bv && oi < bi)) { bv = ov; bi = oi; }
    }
    s = bi;
  }
}

// ---- K7: sparse final update: out[t][z] += 10 for z adjacent to cur[t] ----
__global__ __launch_bounds__(256) void k_out2(float* out, const u32* curz, const u32* bits) {
  int t = blockIdx.x * 4 + (threadIdx.x >> 6);
  int lane = threadIdx.x & 63;
  u32 c = curz[t];
  u64 w = ((const u64*)(bits + (size_t)c * 128))[lane];
  float* p = out + (size_t)t * ZZ + lane * 64;
  while (w) {
    int bpos = __ffsll((unsigned long long)w) - 1;
    p[bpos] += PEN;
    w &= w - 1;
  }
}

extern "C" void kernel_launch(void* const* d_in, const int* in_sizes, int n_in,
                              void* d_out, int out_size, void* d_ws, size_t ws_size,
                              hipStream_t stream) {
  const float* pa    = (const float*)d_in[0];
  const float* times = (const float*)d_in[1];
  const int*   ei    = (const int*)d_in[3];
  const float* W1    = (const float*)d_in[4];
  const float* b1    = (const float*)d_in[5];
  const float* W2    = (const float*)d_in[6];
  const float* b2    = (const float*)d_in[7];
  const float* W3    = (const float*)d_in[8];
  const float* b3    = (const float*)d_in[9];
  float* out = (float*)d_out;
  char* ws = (char*)d_ws;

  u32* bits = (u32*)(ws + WS_BITS);
  u64* gmkey = (u64*)(ws + WS_GMKEY);
  u32* deg  = (u32*)(ws + WS_DEG);
  u16* adjl = (u16*)(ws + WS_ADJL);
  u8*  nchp = (u8*)(ws + WS_NCH);
  float* cvec = (float*)(ws + WS_CVEC);
  float* wvec = (float*)(ws + WS_WVEC);
  float* h2   = (float*)(ws + WS_H2);
  u16* M = (u16*)(ws + WS_M);
  u16* H = (u16*)(ws + WS_H);
  u32* sb   = (u32*)(ws + WS_SB);
  u32* curz = (u32*)(ws + WS_CUR);

  hipLaunchKernelGGL(k_setupA, dim3(545), dim3(256), 0, stream,
                     bits, deg, pa, W1, b1, cvec, wvec);
  hipLaunchKernelGGL(k_edges, dim3(EE / 256 + 16), dim3(256), 0, stream,
                     ei, bits, deg, adjl);
  hipLaunchKernelGGL(k_setupC, dim3(16 + TT / 4), dim3(256), 0, stream,
                     deg, adjl, nchp, times, W2, b2, cvec, wvec, h2);
  hipLaunchKernelGGL(k_raw, dim3(8192), dim3(512), 0, stream, h2, W3, b3, out, gmkey);
  hipLaunchKernelGGL(k_stage1, dim3(NBLK), dim3(512), 0, stream, out, adjl, nchp, gmkey, M);
  hipLaunchKernelGGL(k_super, dim3(NSUP * 4), dim3(256), 0, stream, M, H);
  hipLaunchKernelGGL(k_chase, dim3(1), dim3(64), 0, stream, M, H, sb);
  hipLaunchKernelGGL(k_replay2, dim3(NBLK), dim3(64), 0, stream, out, adjl, nchp, gmkey, sb, curz);
  hipLaunchKernelGGL(k_out2, dim3(TT / 4), dim3(256), 0, stream, out, curz, bits);
}

// Round 17
// 386.492 us; speedup vs baseline: 1.2122x; 1.0336x over previous
//
#include <hip/hip_runtime.h>
#include <hip/hip_bf16.h>
#include <stdint.h>

typedef uint16_t u16;
typedef uint32_t u32;
typedef uint64_t u64;
typedef unsigned char u8;

#define TT 16384
#define ZZ 4096
#define EE 65536
#define LBLK 32
#define NBLK 512          // TT / LBLK
#define SUPW 16
#define NSUP 32           // NBLK / SUPW
#define ADJ_STRIDE 80     // u16 entries per row (max degree ~60 w.h.p.); 20 u64 chunks
#define UCAP 2048         // worklist cap; overflow -> exact dense fallback
#define PEN 10.0f

// ---- ws layout (bytes) ----
#define WS_BITS   0x000000   // u32[4096*128]  2 MB   adjacency bitmask
#define WS_GMKEY  0x200000   // u64[16384]     128 KB scan-key (max,argmax) per r' row
#define WS_DEG    0x220000   // u32[4096]
#define WS_ADJL   0x224000   // u16[4096*80]   640 KB CSR (padded to mult of 4 w/ self)
#define WS_NCH    0x2C4000   // u8[4096]       padded chunk count (deg/4)
#define WS_CVEC   0x2C5000   // f32[128]
#define WS_WVEC   0x2C5200   // f32[128]
#define WS_H2     0x2C5400   // f32[16384*64]  4 MB  (dead after k_raw)
#define WS_M      WS_H2      // u16[512*4096]  4 MB  composed block maps (aliases h2)
#define WS_H      0x6C5400   // u16[32*4096]   256 KB super maps
#define WS_SB     0x705400   // u32[512]
#define WS_CUR    0x705C00   // u32[16384]     cur[t]

// sortable u32: bigger == larger float (total order incl. negatives)
__device__ __forceinline__ u32 sfu(float v) {
  u32 u = __float_as_uint(v);
  return u ^ ((u32)((int)u >> 31) | 0x80000000u);
}
// 44-bit scan key (k_raw/gmkey storage): sfu(v)<<12 | (4095-z)
__device__ __forceinline__ u64 mkkey(float v, u32 z) {
  return ((u64)sfu(v) << 12) | (u64)(4095u - z);
}
__device__ __forceinline__ float key_val(u64 k) {
  u32 sf = (u32)(k >> 12);
  u32 u = (sf & 0x80000000u) ? (sf ^ 0x80000000u) : ~sf;
  return __uint_as_float(u);
}

// one quarter of an eval: strided chunks {part, part+4, ..., part+16} of state s.
// Preloads guarded (R11-proven); nc from LDS table.
// In-register key pair: {hi = sf(value), lo = z^0xFFF} -> u64 max == (val, min-z).
__device__ __forceinline__ u64 eval_part(int s, int part, const u32* keys, u64 gkey,
                                         const u16* adjl, int nc) {
  const u64* alq = (const u64*)(adjl + (size_t)s * ADJ_STRIDE);
  u64 c0 = (part      < nc) ? alq[part]      : 0;
  u64 c1 = (part + 4  < nc) ? alq[part + 4]  : 0;
  u64 c2 = (part + 8  < nc) ? alq[part + 8]  : 0;
  u64 c3 = (part + 12 < nc) ? alq[part + 12] : 0;
  u64 c4 = (part + 16 < nc) ? alq[part + 16] : 0;
  u64 bb = gkey;
#define CM(cv, cnd) if (cnd) {                                                   \
    u32 lo = (u32)(cv), hi = (u32)((cv) >> 32);                                  \
    u32 za = lo & 0xFFFFu, zb = lo >> 16, zc = hi & 0xFFFFu, zd = hi >> 16;      \
    u64 k0 = ((u64)keys[za] << 32) | (u64)(za ^ 0xFFFu);                         \
    u64 k1 = ((u64)keys[zb] << 32) | (u64)(zb ^ 0xFFFu);                         \
    u64 k2 = ((u64)keys[zc] << 32) | (u64)(zc ^ 0xFFFu);                         \
    u64 k3 = ((u64)keys[zd] << 32) | (u64)(zd ^ 0xFFFu);                         \
    u64 t01 = k0 > k1 ? k0 : k1; u64 t23 = k2 > k3 ? k2 : k3;                    \
    u64 tm = t01 > t23 ? t01 : t23;                                              \
    bb = tm > bb ? tm : bb; }
  CM(c0, part < nc) CM(c1, part + 4 < nc) CM(c2, part + 8 < nc)
  CM(c3, part + 12 < nc) CM(c4, part + 16 < nc)
#undef CM
  return bb;
}

// ---- KA: fused {zero bits+gmkey} {deg=0} {block last: cvec/wvec} ----
__global__ __launch_bounds__(256) void k_setupA(u32* bits, u32* deg,
                                                const float* pa, const float* W1,
                                                const float* b1,
                                                float* cvec, float* wvec) {
  __shared__ float pal[512];
  int tid = threadIdx.x;
  if (blockIdx.x < 544) {
    int idx = blockIdx.x * 256 + tid;
    ((uint4*)bits)[idx] = make_uint4(0, 0, 0, 0);
    if (blockIdx.x < 16) deg[blockIdx.x * 256 + tid] = 0;
    return;
  }
  for (int i = tid; i < 512; i += 256) pal[i] = pa[i];
  __syncthreads();
  if (tid < 128) {
    float acc = b1[tid];
    for (int i = 0; i < 512; i++) acc = fmaf(pal[i], W1[(size_t)i * 128 + tid], acc);
    cvec[tid] = acc;
    wvec[tid] = W1[512 * 128 + tid];
  }
}

// ---- K0b: scatter edges + self loops (blocks >= EE/256), deduped via bitmask ----
__global__ void k_edges(const int* ei, u32* bits, u32* deg, u16* adjl) {
  int gb = blockIdx.x;
  if (gb >= EE / 256) {
    int z = (gb - EE / 256) * 256 + threadIdx.x;
    u32 bit = 1u << (z & 31);
    u32 old = atomicOr(&bits[(size_t)z * 128 + (z >> 5)], bit);
    if (!(old & bit)) {
      u32 p = atomicAdd(&deg[z], 1u);
      if (p < ADJ_STRIDE) adjl[(size_t)z * ADJ_STRIDE + p] = (u16)z;
    }
    return;
  }
  int e = gb * 256 + threadIdx.x;
  int u = ei[e], v = ei[EE + e];
#pragma unroll
  for (int dir = 0; dir < 2; dir++) {
    int a = dir ? v : u, b = dir ? u : v;
    u32 bit = 1u << (b & 31);
    u32 old = atomicOr(&bits[(size_t)a * 128 + (b >> 5)], bit);
    if (!(old & bit)) {
      u32 p = atomicAdd(&deg[a], 1u);
      if (p < ADJ_STRIDE) adjl[(size_t)a * ADJ_STRIDE + p] = (u16)b;
    }
  }
}

// ---- KC: fused {blocks 0..15: pad rows to mult4 + chunk count} {rest: h2 MLP} ----
__global__ __launch_bounds__(256) void k_setupC(const u32* deg, u16* adjl, u8* nchp,
                                                const float* times, const float* W2,
                                                const float* b2, const float* cvec,
                                                const float* wvec, float* h2) {
  __shared__ float W2T[64][132];
  __shared__ float h1b[4][128];
  __shared__ float cl[128], wl[128], b2l[64];
  int tid = threadIdx.x;
  if (blockIdx.x < 16) {
    int z = blockIdx.x * 256 + tid;
    int d = (int)deg[z]; if (d > ADJ_STRIDE) d = ADJ_STRIDE;
    int dp = (d + 3) & ~3;
    for (int k = d; k < dp; k++) adjl[(size_t)z * ADJ_STRIDE + k] = (u16)z;
    nchp[z] = (u8)(dp >> 2);
    return;
  }
  for (int idx = tid; idx < 128 * 64; idx += 256) {
    int i = idx >> 6, j = idx & 63;
    W2T[j][i] = W2[idx];
  }
  if (tid < 128) { cl[tid] = cvec[tid]; wl[tid] = wvec[tid]; }
  else if (tid < 192) b2l[tid - 128] = b2[tid - 128];
  __syncthreads();
  int w = tid >> 6, lane = tid & 63;
  int t = (blockIdx.x - 16) * 4 + w;
  float tv = times[t];
  h1b[w][lane]      = fmaxf(fmaf(tv, wl[lane],      cl[lane]),      0.f);
  h1b[w][lane + 64] = fmaxf(fmaf(tv, wl[lane + 64], cl[lane + 64]), 0.f);
  __syncthreads();
  float acc = b2l[lane];
  const float4* hr = (const float4*)&h1b[w][0];
  const float4* Wr = (const float4*)&W2T[lane][0];
#pragma unroll
  for (int i4 = 0; i4 < 32; i4++) {
    float4 a = hr[i4], bb = Wr[i4];
    acc += a.x * bb.x; acc += a.y * bb.y; acc += a.z * bb.z; acc += a.w * bb.w;
  }
  acc = fmaxf(acc, 0.f);
  h2[(size_t)t * 64 + lane] = acc;
}

// ---- K3: r' = h2@W3 + b3 - 10 -> d_out ; fused per-row (max,argmax) ----
// NEW tile 128t x 128z, 512 threads (8t x 4z per thread): staging bytes/output
// -33%, W3 refetch halves. 66 KB LDS -> 2 blocks/CU = 16 waves (proven-flat
// occupancy range per R6/R13).
__global__ __launch_bounds__(512) void k_raw(const float* h2, const float* W3,
                                             const float* b3, float* out,
                                             u64* gmkey) {
  __shared__ float w3t[64][128];   // 32 KB
  __shared__ float h2t[64][132];   // 33.8 KB, transposed [k][t]
  int tid = threadIdx.x;
  int zblk = blockIdx.x & 31, tblk = blockIdx.x >> 5;
  int z0 = zblk * 128, t0 = tblk * 128;
#pragma unroll
  for (int it = 0; it < 4; it++) {
    int f4 = tid + it * 512;                 // 2048 float4 = 8192 f32 (W3 tile)
    int k = f4 >> 5, jj = (f4 & 31) * 4;
    *(float4*)&w3t[k][jj] = *(const float4*)(W3 + (size_t)k * ZZ + z0 + jj);
  }
#pragma unroll
  for (int it = 0; it < 4; it++) {
    int f4 = tid + it * 512;                 // 2048 float4 = 8192 f32 (h2 tile)
    int r = f4 >> 4, kk = (f4 & 15) * 4;     // r 0..127, kk 0..60
    float4 h = *(const float4*)(h2 + (size_t)(t0 + r) * 64 + kk);
    h2t[kk + 0][r] = h.x; h2t[kk + 1][r] = h.y;
    h2t[kk + 2][r] = h.z; h2t[kk + 3][r] = h.w;
  }
  __syncthreads();
  int zq = tid & 31, tq = tid >> 5;          // 32 z-groups x 4z, 16 t-groups x 8t
  float4 acc[8];
#pragma unroll
  for (int r = 0; r < 8; r++) acc[r] = make_float4(0.f, 0.f, 0.f, 0.f);
  for (int k = 0; k < 64; k++) {
    float4 w  = *(const float4*)&w3t[k][zq * 4];
    float4 hA = *(const float4*)&h2t[k][tq * 8];
    float4 hB = *(const float4*)&h2t[k][tq * 8 + 4];
    acc[0].x += hA.x * w.x; acc[0].y += hA.x * w.y; acc[0].z += hA.x * w.z; acc[0].w += hA.x * w.w;
    acc[1].x += hA.y * w.x; acc[1].y += hA.y * w.y; acc[1].z += hA.y * w.z; acc[1].w += hA.y * w.w;
    acc[2].x += hA.z * w.x; acc[2].y += hA.z * w.y; acc[2].z += hA.z * w.z; acc[2].w += hA.z * w.w;
    acc[3].x += hA.w * w.x; acc[3].y += hA.w * w.y; acc[3].z += hA.w * w.z; acc[3].w += hA.w * w.w;
    acc[4].x += hB.x * w.x; acc[4].y += hB.x * w.y; acc[4].z += hB.x * w.z; acc[4].w += hB.x * w.w;
    acc[5].x += hB.y * w.x; acc[5].y += hB.y * w.y; acc[5].z += hB.y * w.z; acc[5].w += hB.y * w.w;
    acc[6].x += hB.z * w.x; acc[6].y += hB.z * w.y; acc[6].z += hB.z * w.z; acc[6].w += hB.z * w.w;
    acc[7].x += hB.w * w.x; acc[7].y += hB.w * w.y; acc[7].z += hB.w * w.z; acc[7].w += hB.w * w.w;
  }
  int z = z0 + zq * 4;
  float4 b3v = *(const float4*)(b3 + z);
  int lane = tid & 63;
  int half = lane >> 5;
#pragma unroll
  for (int r = 0; r < 8; r++) {
    int t = t0 + tq * 8 + r;
    float4 v;
    v.x = acc[r].x + b3v.x - PEN; v.y = acc[r].y + b3v.y - PEN;
    v.z = acc[r].z + b3v.z - PEN; v.w = acc[r].w + b3v.w - PEN;
    *(float4*)(out + (size_t)t * ZZ + z) = v;
    float lv = v.x; u32 lz = (u32)z;
    if (v.y > lv) { lv = v.y; lz = (u32)(z + 1); }
    if (v.z > lv) { lv = v.z; lz = (u32)(z + 2); }
    if (v.w > lv) { lv = v.w; lz = (u32)(z + 3); }
    float mv = lv;
#pragma unroll
    for (int off = 16; off >= 1; off >>= 1) {
      float o = __shfl_xor(mv, off);
      mv = o > mv ? o : mv;
    }
    u64 msk = __ballot(lv == mv);
    u32 hm = (u32)(msk >> (half * 32));
    int fl = __ffs(hm) - 1 + half * 32;
    u32 zbest = __shfl(lz, fl);
    if ((lane & 31) == 0)
      atomicMax((unsigned long long*)&gmkey[t], (unsigned long long)mkkey(mv, zbest));
  }
}

// ---- K4: per-block composed transition maps (R14-proven). ----
__global__ __launch_bounds__(512) void k_stage1(const float* raw, const u16* adjl,
                                                const u8* nchp, const u64* gmkey,
                                                u16* M) {
  __shared__ u32 keys[ZZ];     // 16 KB sortable-f32 table
  __shared__ u16 ev0[ZZ];      // 8 KB first-step map (full domain, persists)
  __shared__ u16 ev[ZZ];       // 8 KB current-step map (image domain)
  __shared__ u16 R[ZZ];        // 8 KB composed remap over image_0
  __shared__ u16 U0[UCAP];     // 4 KB image_0 list (persists)
  __shared__ u16 U[2][UCAP];   // 8 KB worklists
  __shared__ u8  nchl[ZZ];     // 4 KB
  __shared__ u32 markw[128];
  __shared__ u32 mcnt2[2];
  __shared__ u64 gmk[LBLK];
  int tid = threadIdx.x;
  int b = blockIdx.x, t0 = b * LBLK;
  *(u64*)&nchl[tid * 8] = *(const u64*)(nchp + tid * 8);
  if (tid < LBLK) gmk[tid] = gmkey[t0 + tid];
  {
    const float4* src = (const float4*)(raw + (size_t)t0 * ZZ);
    float4 r0 = src[tid], r1 = src[tid + 512];
    ((uint4*)keys)[tid]       = make_uint4(sfu(r0.x), sfu(r0.y), sfu(r0.z), sfu(r0.w));
    ((uint4*)keys)[tid + 512] = make_uint4(sfu(r1.x), sfu(r1.y), sfu(r1.z), sfu(r1.w));
  }
  if (tid < 128) markw[tid] = 0;
  if (tid == 128) { mcnt2[0] = 0; mcnt2[1] = 0; }
  __syncthreads();
  int lane = tid & 63;
  u64 lmask = (((u64)1) << lane) - 1ull;
  int part = tid & 3;
  // ---- iter 0: dense eval -> ev0 (full domain) ----
  {
    const float4* srcn = (const float4*)(raw + (size_t)(t0 + 1) * ZZ);
    float4 p0 = srcn[tid], p1 = srcn[tid + 512];
    u64 gk = gmk[0];
    float gv = key_val(gk) - PEN;
    u64 gkey = ((u64)sfu(gv) << 32) | (u64)(gk & 0xFFFu);
    for (int u = tid; u < ZZ * 4; u += 512) {
      int s = u >> 2;
      u64 pk = eval_part(s, part, keys, gkey, adjl, (int)nchl[s]);
      u64 o1 = __shfl_xor(pk, 1); pk = o1 > pk ? o1 : pk;
      u64 o2 = __shfl_xor(pk, 2); pk = o2 > pk ? o2 : pk;
      if (part == 0) ev0[s] = (u16)(4095u - ((u32)pk & 0xFFFu));
    }
    __syncthreads();
    for (int ch = 0; ch < 8; ch++) {
      u32 ns = ev0[ch * 512 + tid];
      u32 wi = ns >> 5, bit = 1u << (ns & 31);
      u32 old = atomicOr(&markw[wi], bit);
      bool isnew = !(old & bit);
      u64 msk = __ballot(isnew ? 1 : 0);
      u32 base = 0;
      if (lane == 0) base = msk ? atomicAdd(&mcnt2[0], (u32)__popcll(msk)) : 0u;
      base = __shfl(base, 0);
      if (isnew) {
        u32 idx = base + (u32)__popcll(msk & lmask);
        if (idx < UCAP) { U[0][idx] = (u16)ns; U0[idx] = (u16)ns; }
        R[ns] = (u16)ns;
      }
    }
    ((uint4*)keys)[tid]       = make_uint4(sfu(p0.x), sfu(p0.y), sfu(p0.z), sfu(p0.w));
    ((uint4*)keys)[tid + 512] = make_uint4(sfu(p1.x), sfu(p1.y), sfu(p1.z), sfu(p1.w));
    __syncthreads();
  }
  int m0r = (int)mcnt2[0];
  bool full0 = (m0r > UCAP);
  int m0 = full0 ? ZZ : m0r;
  if (full0) {
#pragma unroll
    for (int q = 0; q < 8; q++) {
      int j = tid + q * 512;
      R[j] = (u16)j;
    }
    __syncthreads();
  }
  int m = m0;
  bool dense = full0;
  int pb = 0;
  for (int i = 1; i < LBLK; i++) {
    int t = t0 + i;
    int tn = t + 1; if (tn > TT - 1) tn = TT - 1;
    const float4* srcn = (const float4*)(raw + (size_t)tn * ZZ);
    float4 p0 = srcn[tid], p1 = srcn[tid + 512];
    if (tid < 128) markw[tid] = 0;
    if (tid == 128) mcnt2[pb ^ 1] = 0;
    u64 gk = gmk[i];
    float gv = key_val(gk) - PEN;
    u64 gkey = ((u64)sfu(gv) << 32) | (u64)(gk & 0xFFFu);
    int m4 = m << 2;
    for (int u = tid; u < m4; u += 512) {
      int s = dense ? (u >> 2) : (int)U[pb][u >> 2];
      u64 pk = eval_part(s, part, keys, gkey, adjl, (int)nchl[s]);
      u64 o1 = __shfl_xor(pk, 1); pk = o1 > pk ? o1 : pk;
      u64 o2 = __shfl_xor(pk, 2); pk = o2 > pk ? o2 : pk;
      if (part == 0) ev[s] = (u16)(4095u - ((u32)pk & 0xFFFu));
    }
    __syncthreads();
    for (int u = tid; u < m0; u += 512) {
      int v = full0 ? u : (int)U0[u];
      R[v] = ev[R[v]];
    }
    for (int u = tid; u < m; u += 512) {
      int s = dense ? u : (int)U[pb][u];
      u32 ns = ev[s];
      u32 wi = ns >> 5, bit = 1u << (ns & 31);
      u32 old = atomicOr(&markw[wi], bit);
      bool isnew = !(old & bit);
      u64 msk = __ballot(isnew ? 1 : 0);
      u32 base = 0;
      if (lane == 0) base = msk ? atomicAdd(&mcnt2[pb ^ 1], (u32)__popcll(msk)) : 0u;
      base = __shfl(base, 0);
      if (isnew) {
        u32 idx = base + (u32)__popcll(msk & lmask);
        if (idx < UCAP) U[pb ^ 1][idx] = (u16)ns;
      }
    }
    ((uint4*)keys)[tid]       = make_uint4(sfu(p0.x), sfu(p0.y), sfu(p0.z), sfu(p0.w));
    ((uint4*)keys)[tid + 512] = make_uint4(sfu(p1.x), sfu(p1.y), sfu(p1.z), sfu(p1.w));
    __syncthreads();
    m = (int)mcnt2[pb ^ 1];
    dense = (m > UCAP);
    if (dense) m = ZZ;
    pb ^= 1;
  }
  {
    int j0 = tid * 8;
    u64 w0 = (u64)R[ev0[j0 + 0]]
           | ((u64)R[ev0[j0 + 1]] << 16)
           | ((u64)R[ev0[j0 + 2]] << 32)
           | ((u64)R[ev0[j0 + 3]] << 48);
    u64 w1 = (u64)R[ev0[j0 + 4]]
           | ((u64)R[ev0[j0 + 5]] << 16)
           | ((u64)R[ev0[j0 + 6]] << 32)
           | ((u64)R[ev0[j0 + 7]] << 48);
    u64* md = (u64*)(M + (size_t)b * ZZ);
    md[tid * 2]     = w0;
    md[tid * 2 + 1] = w1;
  }
}

// ---- K5a: compose groups of 16 block-maps into super maps (128 blocks) ----
__global__ __launch_bounds__(256) void k_super(const u16* G, u16* H) {
  int g = blockIdx.x >> 2, qtr = blockIdx.x & 3;
  int tid = threadIdx.x;
  int base = qtr * 1024;
  u32 v[4];
#pragma unroll
  for (int q = 0; q < 4; q++) v[q] = G[(size_t)(g * SUPW) * ZZ + base + tid + q * 256];
  for (int k = 1; k < SUPW; k++) {
    const u16* Gk = G + (size_t)(g * SUPW + k) * ZZ;
#pragma unroll
    for (int q = 0; q < 4; q++) v[q] = Gk[v[q]];
  }
#pragma unroll
  for (int q = 0; q < 4; q++) H[(size_t)g * ZZ + base + tid + q * 256] = (u16)v[q];
}

// ---- K5b: chase super maps then per-group block maps -> block start states ----
__global__ void k_chase(const u16* G, const u16* H, u32* sb) {
  __shared__ u32 ug[NSUP];
  int tid = threadIdx.x;  // 64
  if (tid == 0) {
    u32 s = 0;
    for (int g = 0; g < NSUP; g++) { ug[g] = s; s = H[(size_t)g * ZZ + s]; }
  }
  __syncthreads();
  if (tid < NSUP) {
    u32 s = ug[tid];
    for (int k = 0; k < SUPW; k++) {
      int b = tid * SUPW + k;
      sb[b] = s;
      s = G[(size_t)b * ZZ + s];
    }
  }
}

// ---- K6: one wave per scan-block walks its steps (all blocks co-resident) ----
__global__ __launch_bounds__(64) void k_replay2(const float* out, const u16* adjl,
                                                const u8* nchp, const u64* gmkey,
                                                const u32* sb, u32* curz) {
  int b = blockIdx.x, t0 = b * LBLK;
  int lane = threadIdx.x;
  u32 s = sb[b];
  for (int i = 0; i < LBLK; i++) {
    int t = t0 + i;
    if (lane == 0) curz[t] = s;
    u64 gk = gmkey[t];
    float gv = key_val(gk) - PEN;
    u32 gi = 4095u - (u32)(gk & 0xFFFu);
    int dp = ((int)nchp[s]) << 2;
    const u16* al = adjl + (size_t)s * ADJ_STRIDE;
    const float* r = out + (size_t)t * ZZ;
    float bv = gv; u32 bi = gi;
    if (lane < dp) {
      u32 nb = al[lane]; float v = r[nb];
      if (v > bv || (v == bv && nb < bi)) { bv = v; bi = nb; }
    }
    if (lane + 64 < dp) {
      u32 nb = al[lane + 64]; float v = r[nb];
      if (v > bv || (v == bv && nb < bi)) { bv = v; bi = nb; }
    }
#pragma unroll
    for (int off = 32; off >= 1; off >>= 1) {
      float ov = __shfl_xor(bv, off);
      u32 oi  = __shfl_xor(bi, off);
      if (ov > bv || (ov == bv && oi < bi)) { bv = ov; bi = oi; }
    }
    s = bi;
  }
}

// ---- K7: sparse final update: out[t][z] += 10 for z adjacent to cur[t] ----
__global__ __launch_bounds__(256) void k_out2(float* out, const u32* curz, const u32* bits) {
  int t = blockIdx.x * 4 + (threadIdx.x >> 6);
  int lane = threadIdx.x & 63;
  u32 c = curz[t];
  u64 w = ((const u64*)(bits + (size_t)c * 128))[lane];
  float* p = out + (size_t)t * ZZ + lane * 64;
  while (w) {
    int bpos = __ffsll((unsigned long long)w) - 1;
    p[bpos] += PEN;
    w &= w - 1;
  }
}

extern "C" void kernel_launch(void* const* d_in, const int* in_sizes, int n_in,
                              void* d_out, int out_size, void* d_ws, size_t ws_size,
                              hipStream_t stream) {
  const float* pa    = (const float*)d_in[0];
  const float* times = (const float*)d_in[1];
  const int*   ei    = (const int*)d_in[3];
  const float* W1    = (const float*)d_in[4];
  const float* b1    = (const float*)d_in[5];
  const float* W2    = (const float*)d_in[6];
  const float* b2    = (const float*)d_in[7];
  const float* W3    = (const float*)d_in[8];
  const float* b3    = (const float*)d_in[9];
  float* out = (float*)d_out;
  char* ws = (char*)d_ws;

  u32* bits = (u32*)(ws + WS_BITS);
  u64* gmkey = (u64*)(ws + WS_GMKEY);
  u32* deg  = (u32*)(ws + WS_DEG);
  u16* adjl = (u16*)(ws + WS_ADJL);
  u8*  nchp = (u8*)(ws + WS_NCH);
  float* cvec = (float*)(ws + WS_CVEC);
  float* wvec = (float*)(ws + WS_WVEC);
  float* h2   = (float*)(ws + WS_H2);
  u16* M = (u16*)(ws + WS_M);
  u16* H = (u16*)(ws + WS_H);
  u32* sb   = (u32*)(ws + WS_SB);
  u32* curz = (u32*)(ws + WS_CUR);

  hipLaunchKernelGGL(k_setupA, dim3(545), dim3(256), 0, stream,
                     bits, deg, pa, W1, b1, cvec, wvec);
  hipLaunchKernelGGL(k_edges, dim3(EE / 256 + 16), dim3(256), 0, stream,
                     ei, bits, deg, adjl);
  hipLaunchKernelGGL(k_setupC, dim3(16 + TT / 4), dim3(256), 0, stream,
                     deg, adjl, nchp, times, W2, b2, cvec, wvec, h2);
  hipLaunchKernelGGL(k_raw, dim3(4096), dim3(512), 0, stream, h2, W3, b3, out, gmkey);
  hipLaunchKernelGGL(k_stage1, dim3(NBLK), dim3(512), 0, stream, out, adjl, nchp, gmkey, M);
  hipLaunchKernelGGL(k_super, dim3(NSUP * 4), dim3(256), 0, stream, M, H);
  hipLaunchKernelGGL(k_chase, dim3(1), dim3(64), 0, stream, M, H, sb);
  hipLaunchKernelGGL(k_replay2, dim3(NBLK), dim3(64), 0, stream, out, adjl, nchp, gmkey, sb, curz);
  hipLaunchKernelGGL(k_out2, dim3(TT / 4), dim3(256), 0, stream, out, curz, bits);
}